// Round 1
// baseline (999.539 us; speedup 1.0000x reference)
//
#include <hip/hip_runtime.h>

// 192^3 structure tensor via separable 1D convolutions.
// All reference kernels are rank-1 outer products:
//   gauss3d = g1 (x) g1 (x) g1          (7-tap each axis)
//   kz = d (x) s (x) s  [9,5,5]
//   ky = s (x) d (x) s  [5,9,5]
//   kx = s (x) s (x) d  [5,5,9]
// Factors extracted on-device from the provided 3D kernels (ratio trick).

constexpr int D  = 192;
constexpr int DD = D * D;                  // 36864
constexpr long long V = (long long)D * DD; // 7077888

// coef layout (floats):
//  [0..6]   ga (7, z-gauss)
//  [7..13]  gb (7, y-gauss)
//  [14..20] gc (7, x-gauss)
//  [21..29] az (9, z-deriv for gz)
//  [30..34] bz (5, y-smooth for gz)
//  [35..39] cz (5, x-smooth for gz/gy)
//  [40..44] ay (5, z-smooth for gy)
//  [45..53] by (9, y-deriv for gy)
//  [54..58] cy (5, unused - shared with cz)
//  [59..63] ax (5, z-smooth for gx)
//  [64..68] bx (5, y-smooth for gx)
//  [69..77] cx (9, x-deriv for gx)
__global__ void setup_coef(const float* __restrict__ g3, const float* __restrict__ kz,
                           const float* __restrict__ ky, const float* __restrict__ kx,
                           float* __restrict__ c) {
    if (blockIdx.x != 0 || threadIdx.x != 0) return;
    float Tg = g3[0];
    for (int i = 0; i < 7; ++i) c[0 + i]  = g3[i * 49];
    for (int j = 0; j < 7; ++j) c[7 + j]  = g3[j * 7] / Tg;
    for (int k = 0; k < 7; ++k) c[14 + k] = g3[k] / Tg;
    float Tz = kz[0];                      // kz: [9,5,5] -> i*25 + j*5 + k
    for (int i = 0; i < 9; ++i) c[21 + i] = kz[i * 25];
    for (int j = 0; j < 5; ++j) c[30 + j] = kz[j * 5] / Tz;
    for (int k = 0; k < 5; ++k) c[35 + k] = kz[k] / Tz;
    float Ty = ky[0];                      // ky: [5,9,5] -> i*45 + j*5 + k
    for (int i = 0; i < 5; ++i) c[40 + i] = ky[i * 45];
    for (int j = 0; j < 9; ++j) c[45 + j] = ky[j * 5] / Ty;
    for (int k = 0; k < 5; ++k) c[54 + k] = ky[k] / Ty;
    float Tx = kx[0];                      // kx: [5,5,9] -> i*45 + j*9 + k
    for (int i = 0; i < 5; ++i) c[59 + i] = kx[i * 45];
    for (int j = 0; j < 5; ++j) c[64 + j] = kx[j * 9] / Tx;
    for (int k = 0; k < 9; ++k) c[69 + k] = kx[k] / Tx;
}

// 1D cross-correlation along AXIS (0=z,1=y,2=x), zero-padded, "same" output.
template <int K, int AXIS>
__global__ __launch_bounds__(256) void conv1d_kernel(const float* __restrict__ in,
                                                     float* __restrict__ out,
                                                     const float* __restrict__ wco) {
    long long idx = (long long)blockIdx.x * blockDim.x + threadIdx.x;
    if (idx >= V) return;
    const int x = (int)(idx % D);
    const int y = (int)((idx / D) % D);
    const int z = (int)(idx / DD);
    constexpr int R = (K - 1) / 2;
    int pos;
    long long stride;
    if (AXIS == 0)      { pos = z; stride = DD; }
    else if (AXIS == 1) { pos = y; stride = D;  }
    else                { pos = x; stride = 1;  }
    float w[K];
#pragma unroll
    for (int k = 0; k < K; ++k) w[k] = wco[k];
    float acc = 0.0f;
#pragma unroll
    for (int k = 0; k < K; ++k) {
        const int p = pos + k - R;
        if (p >= 0 && p < D) acc += w[k] * in[idx + (long long)(k - R) * stride];
    }
    out[idx] = acc;
}

// In-place: ch0 holds gz, ch3 holds gy, ch5 holds gx on entry.
__global__ __launch_bounds__(256) void products_kernel(float* __restrict__ out) {
    long long i = (long long)blockIdx.x * blockDim.x + threadIdx.x;
    if (i >= V) return;
    const float gz = out[0 * V + i];
    const float gy = out[3 * V + i];
    const float gx = out[5 * V + i];
    out[0 * V + i] = gz * gz;
    out[1 * V + i] = gy * gz;
    out[2 * V + i] = gx * gz;
    out[3 * V + i] = gy * gy;
    out[4 * V + i] = gx * gy;
    out[5 * V + i] = gx * gx;
}

extern "C" void kernel_launch(void* const* d_in, const int* in_sizes, int n_in,
                              void* d_out, int out_size, void* d_ws, size_t ws_size,
                              hipStream_t stream) {
    const float* x  = (const float*)d_in[0];
    const float* g3 = (const float*)d_in[1];
    const float* kz = (const float*)d_in[2];
    const float* ky = (const float*)d_in[3];
    const float* kx = (const float*)d_in[4];
    float* out = (float*)d_out;

    float* coef = (float*)d_ws;
    float* W0 = coef + 128;
    float* W1 = W0 + V;

    setup_coef<<<1, 64, 0, stream>>>(g3, kz, ky, kx, coef);

    const int B = 256;
    const int G = (int)(V / B);   // 7077888 / 256 = 27648, exact

    const float* ga = coef + 0;
    const float* gb = coef + 7;
    const float* gc = coef + 14;
    const float* az = coef + 21;
    const float* bz = coef + 30;
    const float* cz = coef + 35;
    const float* ay = coef + 40;
    const float* by = coef + 45;
    const float* ax = coef + 59;
    const float* bx = coef + 64;
    const float* cx = coef + 69;

    float* xs = out + 4 * V;  // park smoothed input in ch4 (free until products)

    // Stage 1: Gaussian pre-smooth  xs = Gz Gy Gx * x
    conv1d_kernel<7, 0><<<G, B, 0, stream>>>(x,  W0, ga);
    conv1d_kernel<7, 1><<<G, B, 0, stream>>>(W0, W1, gb);
    conv1d_kernel<7, 2><<<G, B, 0, stream>>>(W1, xs, gc);

    // Stage 2: gradients (gz -> ch0, gy -> ch3, gx -> ch5)
    conv1d_kernel<5, 2><<<G, B, 0, stream>>>(xs, W0, cz);          // A  = Sx(xs)
    conv1d_kernel<5, 1><<<G, B, 0, stream>>>(W0, W1, bz);          // B  = Sy(A)
    conv1d_kernel<9, 0><<<G, B, 0, stream>>>(W1, out + 0 * V, az); // gz = Dz(B)
    conv1d_kernel<9, 1><<<G, B, 0, stream>>>(W0, W1, by);          // C  = Dy(A)
    conv1d_kernel<5, 0><<<G, B, 0, stream>>>(W1, out + 3 * V, ay); // gy = Sz(C)
    conv1d_kernel<9, 2><<<G, B, 0, stream>>>(xs, W0, cx);          // E  = Dx(xs)
    conv1d_kernel<5, 1><<<G, B, 0, stream>>>(W0, W1, bx);          // F  = Sy(E)
    conv1d_kernel<5, 0><<<G, B, 0, stream>>>(W1, out + 5 * V, ax); // gx = Sz(F)

    // Stage 3: outer products in-place (fills all 6 channels)
    products_kernel<<<G, B, 0, stream>>>(out);

    // Stage 4: grouped Gaussian smoothing of each tensor component
    for (int c = 0; c < 6; ++c) {
        conv1d_kernel<7, 0><<<G, B, 0, stream>>>(out + c * V, W0, ga);
        conv1d_kernel<7, 1><<<G, B, 0, stream>>>(W0, W1, gb);
        conv1d_kernel<7, 2><<<G, B, 0, stream>>>(W1, out + c * V, gc);
    }
}

// Round 2
// 312.314 us; speedup vs baseline: 3.2004x; 3.2004x over previous
//
#include <hip/hip_runtime.h>

// 192^3 structure tensor via separable 1D convolutions, fused passes.
// gauss3d = g1(x)g1(x)g1 ; kz = d(x)s(x)s ; ky = s(x)d(x)s ; kx = s(x)s(x)d
// Pipeline (9 dispatches):
//   S0: setup_coef (extract 1D factors via ratio trick)
//   S1: zconv7(x -> ws0) ; yxconv<7,7>(ws0 -> out4=xs)
//   S2: grad_yx(xs -> T1,T2,T3 in ws)   [fused Sx/Dx + Sy/Dy, 3 outputs]
//   S3: zgrad_prod(T1,T2,T3 -> out ch0..5)  [fused Dz/Sz + products]
//   S4: 2 x { zconv7 (3ch batched, out -> ws) ; yxconv<7,7> (3ch, ws -> out) }

constexpr int D  = 192;
constexpr int DD = D * D;                  // 36864
constexpr long long V = (long long)D * DD; // 7077888

// coef layout (floats):
//  [0..6] ga  [7..13] gb  [14..20] gc   (gauss z,y,x)
//  [21..29] az (9)  [30..34] bz (5)  [35..39] cz (5)
//  [40..44] ay (5)  [45..53] by (9)  [54..58] cy (5, dup of cz)
//  [59..63] ax (5)  [64..68] bx (5)  [69..77] cx (9)
__global__ void setup_coef(const float* __restrict__ g3, const float* __restrict__ kz,
                           const float* __restrict__ ky, const float* __restrict__ kx,
                           float* __restrict__ c) {
    if (blockIdx.x != 0 || threadIdx.x != 0) return;
    float Tg = g3[0];
    for (int i = 0; i < 7; ++i) c[0 + i]  = g3[i * 49];
    for (int j = 0; j < 7; ++j) c[7 + j]  = g3[j * 7] / Tg;
    for (int k = 0; k < 7; ++k) c[14 + k] = g3[k] / Tg;
    float Tz = kz[0];                      // kz: [9,5,5]
    for (int i = 0; i < 9; ++i) c[21 + i] = kz[i * 25];
    for (int j = 0; j < 5; ++j) c[30 + j] = kz[j * 5] / Tz;
    for (int k = 0; k < 5; ++k) c[35 + k] = kz[k] / Tz;
    float Ty = ky[0];                      // ky: [5,9,5]
    for (int i = 0; i < 5; ++i) c[40 + i] = ky[i * 45];
    for (int j = 0; j < 9; ++j) c[45 + j] = ky[j * 5] / Ty;
    for (int k = 0; k < 5; ++k) c[54 + k] = ky[k] / Ty;
    float Tx = kx[0];                      // kx: [5,5,9]
    for (int i = 0; i < 5; ++i) c[59 + i] = kx[i * 45];
    for (int j = 0; j < 5; ++j) c[64 + j] = kx[j * 9] / Tx;
    for (int k = 0; k < 9; ++k) c[69 + k] = kx[k] / Tx;
}

// ---- z-axis 1D conv, float4-vectorized, channels via blockIdx.y ----
template <int K>
__global__ __launch_bounds__(256) void zconv(const float* __restrict__ in,
                                             float* __restrict__ out,
                                             const float* __restrict__ wco,
                                             long long inCh, long long outCh) {
    const float* src = in  + (long long)blockIdx.y * inCh;
    float*       dst = out + (long long)blockIdx.y * outCh;
    const int i4 = (blockIdx.x * 256 + threadIdx.x) * 4;   // < V, fits int
    const int z = i4 / DD;
    constexpr int R = (K - 1) / 2;
    float w[K];
#pragma unroll
    for (int k = 0; k < K; ++k) w[k] = wco[k];
    float4 acc = {0.f, 0.f, 0.f, 0.f};
#pragma unroll
    for (int k = 0; k < K; ++k) {
        const int p = z + k - R;
        if (p >= 0 && p < D) {
            float4 v = *(const float4*)(src + i4 + (k - R) * DD);
            acc.x += w[k] * v.x; acc.y += w[k] * v.y;
            acc.z += w[k] * v.z; acc.w += w[k] * v.w;
        }
    }
    *(float4*)(dst + i4) = acc;
}

// ---- shared tile loader: A[40][48] = slice z rows ty-4..ty+35, cols tx-8..tx+39 ----
__device__ inline void load_tile(const float* __restrict__ src, float A[40][48],
                                 int ty, int tx) {
    for (int li = threadIdx.x; li < 40 * 12; li += 256) {
        const int r  = li / 12, c4 = li % 12;
        const int gy = ty - 4 + r;
        const int gxb = tx - 8 + c4 * 4;
        float4 v = {0.f, 0.f, 0.f, 0.f};
        if (gy >= 0 && gy < D) {
            if (gxb >= 0 && gxb + 3 < D) {
                v = *(const float4*)(src + gy * D + gxb);
            } else {
                float* pv = (float*)&v;
                for (int j = 0; j < 4; ++j) {
                    const int gx = gxb + j;
                    if (gx >= 0 && gx < D) pv[j] = src[gy * D + gx];
                }
            }
        }
        *(float4*)&A[r][c4 * 4] = v;
    }
}

// ---- fused y*x 2D conv on one z-slice; channels via blockIdx.z ----
template <int KY, int KX>
__global__ __launch_bounds__(256) void yxconv(const float* __restrict__ in,
                                              float* __restrict__ out,
                                              const float* __restrict__ wyc,
                                              const float* __restrict__ wxc,
                                              long long inCh, long long outCh) {
    constexpr int RY = (KY - 1) / 2, RX = (KX - 1) / 2;
    __shared__ float A[40][48];
    __shared__ float B[40][32];
    const int tile = blockIdx.x;
    const int tx = (tile % 6) * 32, ty = (tile / 6) * 32;
    const int z = blockIdx.y;
    const float* src = in + (long long)blockIdx.z * inCh + (long long)z * DD;
    load_tile(src, A, ty, tx);
    float wx[KX], wy[KY];
#pragma unroll
    for (int k = 0; k < KX; ++k) wx[k] = wxc[k];
#pragma unroll
    for (int k = 0; k < KY; ++k) wy[k] = wyc[k];
    __syncthreads();
    for (int li = threadIdx.x; li < 40 * 32; li += 256) {
        const int r = li / 32, c = li % 32;
        float acc = 0.f;
#pragma unroll
        for (int k = 0; k < KX; ++k) acc += wx[k] * A[r][c + 8 - RX + k];
        B[r][c] = acc;
    }
    __syncthreads();
    float* dst = out + (long long)blockIdx.z * outCh + (long long)z * DD;
    for (int li = threadIdx.x; li < 32 * 32; li += 256) {
        const int r = li / 32, c = li % 32;
        float acc = 0.f;
#pragma unroll
        for (int k = 0; k < KY; ++k) acc += wy[k] * B[r + 4 - RY + k][c];
        dst[(ty + r) * D + tx + c] = acc;
    }
}

// ---- fused gradient xy-prefilters: xs -> T1 = Sy·Sx, T2 = Dy·Sx, T3 = Sy·Dx ----
__global__ __launch_bounds__(256) void grad_yx(const float* __restrict__ xs,
                                               float* __restrict__ T1,
                                               float* __restrict__ T2,
                                               float* __restrict__ T3,
                                               const float* __restrict__ coef) {
    __shared__ float A[40][48];
    __shared__ float X1[40][32];
    __shared__ float X2[40][32];
    const int tile = blockIdx.x;
    const int tx = (tile % 6) * 32, ty = (tile / 6) * 32;
    const int z = blockIdx.y;
    const float* src = xs + (long long)z * DD;
    load_tile(src, A, ty, tx);
    float cz[5], cx[9], bz[5], by[9], bx[5];
#pragma unroll
    for (int k = 0; k < 5; ++k) cz[k] = coef[35 + k];
#pragma unroll
    for (int k = 0; k < 9; ++k) cx[k] = coef[69 + k];
#pragma unroll
    for (int k = 0; k < 5; ++k) bz[k] = coef[30 + k];
#pragma unroll
    for (int k = 0; k < 9; ++k) by[k] = coef[45 + k];
#pragma unroll
    for (int k = 0; k < 5; ++k) bx[k] = coef[64 + k];
    __syncthreads();
    for (int li = threadIdx.x; li < 40 * 32; li += 256) {
        const int r = li / 32, c = li % 32;
        float a1 = 0.f, a2 = 0.f;
#pragma unroll
        for (int k = 0; k < 5; ++k) a1 += cz[k] * A[r][c + 8 - 2 + k];
#pragma unroll
        for (int k = 0; k < 9; ++k) a2 += cx[k] * A[r][c + 8 - 4 + k];
        X1[r][c] = a1;
        X2[r][c] = a2;
    }
    __syncthreads();
    const long long zofs = (long long)z * DD;
    for (int li = threadIdx.x; li < 32 * 32; li += 256) {
        const int r = li / 32, c = li % 32;
        float t1 = 0.f, t2 = 0.f, t3 = 0.f;
#pragma unroll
        for (int k = 0; k < 5; ++k) t1 += bz[k] * X1[r + 4 - 2 + k][c];
#pragma unroll
        for (int k = 0; k < 9; ++k) t2 += by[k] * X1[r + 4 - 4 + k][c];
#pragma unroll
        for (int k = 0; k < 5; ++k) t3 += bx[k] * X2[r + 4 - 2 + k][c];
        const long long o = zofs + (ty + r) * D + tx + c;
        T1[o] = t1; T2[o] = t2; T3[o] = t3;
    }
}

// ---- fused gradient z-convs + structure-tensor products ----
__global__ __launch_bounds__(256) void zgrad_prod(const float* __restrict__ T1,
                                                  const float* __restrict__ T2,
                                                  const float* __restrict__ T3,
                                                  float* __restrict__ out,
                                                  const float* __restrict__ coef) {
    const int i4 = (blockIdx.x * 256 + threadIdx.x) * 4;
    const int z = i4 / DD;
    float az[9], ay[5], ax[5];
#pragma unroll
    for (int k = 0; k < 9; ++k) az[k] = coef[21 + k];
#pragma unroll
    for (int k = 0; k < 5; ++k) ay[k] = coef[40 + k];
#pragma unroll
    for (int k = 0; k < 5; ++k) ax[k] = coef[59 + k];
    float4 gz = {0.f,0.f,0.f,0.f}, gy = {0.f,0.f,0.f,0.f}, gx = {0.f,0.f,0.f,0.f};
#pragma unroll
    for (int k = 0; k < 9; ++k) {
        const int p = z + k - 4;
        if (p >= 0 && p < D) {
            float4 v = *(const float4*)(T1 + i4 + (k - 4) * DD);
            gz.x += az[k] * v.x; gz.y += az[k] * v.y;
            gz.z += az[k] * v.z; gz.w += az[k] * v.w;
        }
    }
#pragma unroll
    for (int k = 0; k < 5; ++k) {
        const int p = z + k - 2;
        if (p >= 0 && p < D) {
            float4 v = *(const float4*)(T2 + i4 + (k - 2) * DD);
            gy.x += ay[k] * v.x; gy.y += ay[k] * v.y;
            gy.z += ay[k] * v.z; gy.w += ay[k] * v.w;
            float4 u = *(const float4*)(T3 + i4 + (k - 2) * DD);
            gx.x += ax[k] * u.x; gx.y += ax[k] * u.y;
            gx.z += ax[k] * u.z; gx.w += ax[k] * u.w;
        }
    }
    float4 r;
    r.x = gz.x*gz.x; r.y = gz.y*gz.y; r.z = gz.z*gz.z; r.w = gz.w*gz.w;
    *(float4*)(out + 0*V + i4) = r;
    r.x = gy.x*gz.x; r.y = gy.y*gz.y; r.z = gy.z*gz.z; r.w = gy.w*gz.w;
    *(float4*)(out + 1*V + i4) = r;
    r.x = gx.x*gz.x; r.y = gx.y*gz.y; r.z = gx.z*gz.z; r.w = gx.w*gz.w;
    *(float4*)(out + 2*V + i4) = r;
    r.x = gy.x*gy.x; r.y = gy.y*gy.y; r.z = gy.z*gy.z; r.w = gy.w*gy.w;
    *(float4*)(out + 3*V + i4) = r;
    r.x = gx.x*gy.x; r.y = gx.y*gy.y; r.z = gx.z*gy.z; r.w = gx.w*gy.w;
    *(float4*)(out + 4*V + i4) = r;
    r.x = gx.x*gx.x; r.y = gx.y*gx.y; r.z = gx.z*gx.z; r.w = gx.w*gx.w;
    *(float4*)(out + 5*V + i4) = r;
}

extern "C" void kernel_launch(void* const* d_in, const int* in_sizes, int n_in,
                              void* d_out, int out_size, void* d_ws, size_t ws_size,
                              hipStream_t stream) {
    const float* x  = (const float*)d_in[0];
    const float* g3 = (const float*)d_in[1];
    const float* kz = (const float*)d_in[2];
    const float* ky = (const float*)d_in[3];
    const float* kx = (const float*)d_in[4];
    float* out = (float*)d_out;

    float* coef = (float*)d_ws;
    float* W0 = coef + 128;
    float* W1 = W0 + V;
    float* W2 = W1 + V;

    setup_coef<<<1, 64, 0, stream>>>(g3, kz, ky, kx, coef);

    const float* ga = coef + 0;
    const float* gb = coef + 7;
    const float* gc = coef + 14;

    const int GZ = (int)(V / 4 / 256);       // 6912, exact
    dim3 tiles(36, D, 1);                    // 6x6 xy tiles, 192 z-slices

    float* xs = out + 4 * V;  // park smoothed input in ch4

    // S1: Gaussian pre-smooth  xs = Gy Gx (Gz x)
    zconv<7><<<dim3(GZ, 1), 256, 0, stream>>>(x, W0, ga, V, V);
    yxconv<7, 7><<<tiles, 256, 0, stream>>>(W0, xs, gb, gc, V, V);

    // S2: gradient xy-prefilters (one fused kernel, 3 outputs)
    grad_yx<<<tiles, 256, 0, stream>>>(xs, W0, W1, W2, coef);

    // S3: gradient z-filters + products -> all 6 channels
    zgrad_prod<<<dim3(GZ, 1), 256, 0, stream>>>(W0, W1, W2, out, coef);

    // S4: grouped Gaussian smoothing, 3 channels per batch
    for (int cb = 0; cb < 6; cb += 3) {
        zconv<7><<<dim3(GZ, 3), 256, 0, stream>>>(out + (long long)cb * V, W0, ga, V, V);
        yxconv<7, 7><<<dim3(36, D, 3), 256, 0, stream>>>(W0, out + (long long)cb * V, gb, gc, V, V);
    }
}

// Round 3
// 289.896 us; speedup vs baseline: 3.4479x; 1.0773x over previous
//
#include <hip/hip_runtime.h>

// 192^3 structure tensor, fully fused z-streaming pipeline (4 dispatches):
//   S0: setup_coef   (extract 1D rank-1 factors from the provided 3D kernels)
//   S1: blur3d       x -> xs           (x,y conv per slice in LDS; z via 7-ring)
//   S2: gradprod3d   xs -> P[6]        (Sx/Dx, Sy/Dy per slice; Dz/Sz via 9-rings; products)
//   S3: blur3d x6ch  P -> out          (grouped Gaussian smoothing, one dispatch)

constexpr int D  = 192;
constexpr int DD = D * D;                  // 36864
constexpr long long V = (long long)D * DD; // 7077888

// coef layout (floats):
//  [0..6] ga  [7..13] gb  [14..20] gc   (gauss z,y,x)
//  [21..29] az (9)  [30..34] bz (5)  [35..39] cz (5)
//  [40..44] ay (5)  [45..53] by (9)  [54..58] cy (5, dup)
//  [59..63] ax (5)  [64..68] bx (5)  [69..77] cx (9)
__global__ void setup_coef(const float* __restrict__ g3, const float* __restrict__ kz,
                           const float* __restrict__ ky, const float* __restrict__ kx,
                           float* __restrict__ c) {
    if (blockIdx.x != 0 || threadIdx.x != 0) return;
    float Tg = g3[0];
    for (int i = 0; i < 7; ++i) c[0 + i]  = g3[i * 49];
    for (int j = 0; j < 7; ++j) c[7 + j]  = g3[j * 7] / Tg;
    for (int k = 0; k < 7; ++k) c[14 + k] = g3[k] / Tg;
    float Tz = kz[0];                      // kz: [9,5,5]
    for (int i = 0; i < 9; ++i) c[21 + i] = kz[i * 25];
    for (int j = 0; j < 5; ++j) c[30 + j] = kz[j * 5] / Tz;
    for (int k = 0; k < 5; ++k) c[35 + k] = kz[k] / Tz;
    float Ty = ky[0];                      // ky: [5,9,5]
    for (int i = 0; i < 5; ++i) c[40 + i] = ky[i * 45];
    for (int j = 0; j < 9; ++j) c[45 + j] = ky[j * 5] / Ty;
    for (int k = 0; k < 5; ++k) c[54 + k] = ky[k] / Ty;
    float Tx = kx[0];                      // kx: [5,5,9]
    for (int i = 0; i < 5; ++i) c[59 + i] = kx[i * 45];
    for (int j = 0; j < 5; ++j) c[64 + j] = kx[j * 9] / Tx;
    for (int k = 0; k < 9; ++k) c[69 + k] = kx[k] / Tx;
}

// Load a (rows x 40)-float region of one z-slice into LDS, zero-padded.
// x0 must be 4-aligned (tile origins are multiples of 32, minus 4).
__device__ inline void load_slice(const float* __restrict__ src, float* __restrict__ dst,
                                  int rows, int y0, int x0) {
    const int nq = rows * 10;
    for (int li = threadIdx.x; li < nq; li += 256) {
        const int r = li / 10, q = li % 10;
        const int gy = y0 + r, gx = x0 + q * 4;
        float4 v = {0.f, 0.f, 0.f, 0.f};
        if (gy >= 0 && gy < D) {
            if (gx >= 0 && gx + 3 < D) {
                v = *(const float4*)(src + gy * D + gx);
            } else {
                float* pv = (float*)&v;
                for (int j = 0; j < 4; ++j) {
                    const int g = gx + j;
                    if (g >= 0 && g < D) pv[j] = src[gy * D + g];
                }
            }
        }
        *(float4*)&dst[r * 40 + q * 4] = v;
    }
}

// ---- fused separable 3D Gaussian blur, z-streaming, 32x32 xy tile ----
// grid: (36 xy-tiles, 192/SEG z-segments, channels)
template <int SEG>
__global__ __launch_bounds__(256) void blur3d(const float* __restrict__ in,
                                              float* __restrict__ out,
                                              const float* __restrict__ coef,
                                              long long inCh, long long outCh) {
    __shared__ float raw[38 * 40];
    __shared__ float xt[38][32];
    __shared__ float ring[7][32][32];
    const int tx0 = (blockIdx.x % 6) * 32, ty0 = (blockIdx.x / 6) * 32;
    const int z0 = blockIdx.y * SEG;
    const float* src = in + (long long)blockIdx.z * inCh;
    float* dst = out + (long long)blockIdx.z * outCh;
    float ga[7], gb[7], gc[7];
#pragma unroll
    for (int k = 0; k < 7; ++k) { ga[k] = coef[k]; gb[k] = coef[7 + k]; gc[k] = coef[14 + k]; }
    const int rr = threadIdx.x >> 3;          // 0..31
    const int cc = (threadIdx.x & 7) * 4;     // 0..28

    for (int p = z0 - 3; p < z0 + SEG + 3; ++p) {
        const int slot = (p + 7) % 7;
        const bool inz = (p >= 0 && p < D);
        __syncthreads();   // ring[slot] readers from prev output done; raw/xt reuse safe
        if (inz) load_slice(src + (long long)p * DD, raw, 38, ty0 - 3, tx0 - 4);
        __syncthreads();
        if (inz) {
            for (int li = threadIdx.x; li < 38 * 32; li += 256) {
                const int r = li >> 5, c = li & 31;
                float a = 0.f;
#pragma unroll
                for (int k = 0; k < 7; ++k) a += gc[k] * raw[r * 40 + c + k + 1];
                xt[r][c] = a;
            }
        }
        __syncthreads();
        if (inz) {
            float4 a = {0.f, 0.f, 0.f, 0.f};
#pragma unroll
            for (int k = 0; k < 7; ++k) {
                const float4 v = *(const float4*)&xt[rr + k][cc];
                a.x += gb[k] * v.x; a.y += gb[k] * v.y;
                a.z += gb[k] * v.z; a.w += gb[k] * v.w;
            }
            *(float4*)&ring[slot][rr][cc] = a;
        } else {
            *(float4*)&ring[slot][rr][cc] = make_float4(0.f, 0.f, 0.f, 0.f);
        }
        const int z = p - 3;
        if (z >= z0 && z < z0 + SEG) {
            __syncthreads();   // ring[slot] just written, needed below
            float4 a = {0.f, 0.f, 0.f, 0.f};
#pragma unroll
            for (int k = 0; k < 7; ++k) {
                const int s = (z + k - 3 + 7) % 7;
                const float4 v = *(const float4*)&ring[s][rr][cc];
                a.x += ga[k] * v.x; a.y += ga[k] * v.y;
                a.z += ga[k] * v.z; a.w += ga[k] * v.w;
            }
            *(float4*)(dst + (long long)z * DD + (ty0 + rr) * D + tx0 + cc) = a;
        }
    }
}

// ---- fused gradients + structure-tensor products, z-streaming, 32x16 xy tile ----
// grid: (72 xy-tiles, 192/SEG z-segments)
template <int SEG>
__global__ __launch_bounds__(256) void gradprod3d(const float* __restrict__ xs,
                                                  float* __restrict__ P,
                                                  const float* __restrict__ coef) {
    __shared__ float raw[24 * 40];
    __shared__ float X1[24][32];
    __shared__ float X2[24][32];
    __shared__ float T1r[9][16][32];
    __shared__ float T2r[9][16][32];
    __shared__ float T3r[9][16][32];
    const int tx0 = (blockIdx.x % 6) * 32, ty0 = (blockIdx.x / 6) * 16;
    const int z0 = blockIdx.y * SEG;
    float az[9], ay[5], ax[5], bz[5], by[9], bx[5], czc[5], cxc[9];
#pragma unroll
    for (int k = 0; k < 9; ++k) az[k] = coef[21 + k];
#pragma unroll
    for (int k = 0; k < 5; ++k) ay[k] = coef[40 + k];
#pragma unroll
    for (int k = 0; k < 5; ++k) ax[k] = coef[59 + k];
#pragma unroll
    for (int k = 0; k < 5; ++k) bz[k] = coef[30 + k];
#pragma unroll
    for (int k = 0; k < 9; ++k) by[k] = coef[45 + k];
#pragma unroll
    for (int k = 0; k < 5; ++k) bx[k] = coef[64 + k];
#pragma unroll
    for (int k = 0; k < 5; ++k) czc[k] = coef[35 + k];
#pragma unroll
    for (int k = 0; k < 9; ++k) cxc[k] = coef[69 + k];
    const int rr = threadIdx.x >> 4;            // 0..15
    const int cc = (threadIdx.x & 15) * 2;      // 0..30

    for (int p = z0 - 4; p < z0 + SEG + 4; ++p) {
        const int slot = (p + 9) % 9;
        const bool inz = (p >= 0 && p < D);
        __syncthreads();
        if (inz) load_slice(xs + (long long)p * DD, raw, 24, ty0 - 4, tx0 - 4);
        __syncthreads();
        if (inz) {
            for (int li = threadIdx.x; li < 24 * 32; li += 256) {
                const int r = li >> 5, c = li & 31;
                float a1 = 0.f, a2 = 0.f;
#pragma unroll
                for (int k = 0; k < 5; ++k) a1 += czc[k] * raw[r * 40 + c + k + 2];
#pragma unroll
                for (int k = 0; k < 9; ++k) a2 += cxc[k] * raw[r * 40 + c + k];
                X1[r][c] = a1;
                X2[r][c] = a2;
            }
        }
        __syncthreads();
        for (int li = threadIdx.x; li < 512; li += 256) {
            const int r = li >> 5, c = li & 31;
            float t1 = 0.f, t2 = 0.f, t3 = 0.f;
            if (inz) {
#pragma unroll
                for (int k = 0; k < 5; ++k) t1 += bz[k] * X1[r + k + 2][c];
#pragma unroll
                for (int k = 0; k < 9; ++k) t2 += by[k] * X1[r + k][c];
#pragma unroll
                for (int k = 0; k < 5; ++k) t3 += bx[k] * X2[r + k + 2][c];
            }
            T1r[slot][r][c] = t1;
            T2r[slot][r][c] = t2;
            T3r[slot][r][c] = t3;
        }
        const int z = p - 4;
        if (z >= z0 && z < z0 + SEG) {
            __syncthreads();
            float gz0 = 0.f, gz1 = 0.f, gy0 = 0.f, gy1 = 0.f, gx0 = 0.f, gx1 = 0.f;
#pragma unroll
            for (int k = 0; k < 9; ++k) {
                const int s = (z + k - 4 + 9) % 9;
                const float2 t = *(const float2*)&T1r[s][rr][cc];
                gz0 += az[k] * t.x; gz1 += az[k] * t.y;
            }
#pragma unroll
            for (int k = 0; k < 5; ++k) {
                const int s = (z + k - 2 + 9) % 9;
                const float2 t2v = *(const float2*)&T2r[s][rr][cc];
                gy0 += ay[k] * t2v.x; gy1 += ay[k] * t2v.y;
                const float2 t3v = *(const float2*)&T3r[s][rr][cc];
                gx0 += ax[k] * t3v.x; gx1 += ax[k] * t3v.y;
            }
            float* o = P + (long long)z * DD + (ty0 + rr) * D + tx0 + cc;
            float2 w;
            w.x = gz0 * gz0; w.y = gz1 * gz1; *(float2*)(o + 0 * V) = w;
            w.x = gy0 * gz0; w.y = gy1 * gz1; *(float2*)(o + 1 * V) = w;
            w.x = gx0 * gz0; w.y = gx1 * gz1; *(float2*)(o + 2 * V) = w;
            w.x = gy0 * gy0; w.y = gy1 * gy1; *(float2*)(o + 3 * V) = w;
            w.x = gx0 * gy0; w.y = gx1 * gy1; *(float2*)(o + 4 * V) = w;
            w.x = gx0 * gx0; w.y = gx1 * gx1; *(float2*)(o + 5 * V) = w;
        }
    }
}

extern "C" void kernel_launch(void* const* d_in, const int* in_sizes, int n_in,
                              void* d_out, int out_size, void* d_ws, size_t ws_size,
                              hipStream_t stream) {
    const float* x  = (const float*)d_in[0];
    const float* g3 = (const float*)d_in[1];
    const float* kz = (const float*)d_in[2];
    const float* ky = (const float*)d_in[3];
    const float* kx = (const float*)d_in[4];
    float* out = (float*)d_out;

    float* coef = (float*)d_ws;
    float* P = coef + 128;          // 6*V floats of scratch for products
    float* xs = out + 4 * V;        // park smoothed input in out ch4 (free until S3 writes)

    setup_coef<<<1, 64, 0, stream>>>(g3, kz, ky, kx, coef);

    // S1: Gaussian pre-smooth  x -> xs
    blur3d<24><<<dim3(36, 8, 1), 256, 0, stream>>>(x, xs, coef, V, V);

    // S2: gradients + products  xs -> P (6 channels)
    gradprod3d<32><<<dim3(72, 6), 256, 0, stream>>>(xs, P, coef);

    // S3: grouped Gaussian smoothing  P -> out (all 6 channels, one dispatch)
    blur3d<48><<<dim3(36, 4, 6), 256, 0, stream>>>(P, out, coef, V, V);
}

// Round 4
// 187.845 us; speedup vs baseline: 5.3211x; 1.5433x over previous
//
#include <hip/hip_runtime.h>

// 192^3 structure tensor, fused z-streaming pipeline (4 dispatches):
//   S0: setup_coef   (extract 1D rank-1 factors from the provided 3D kernels)
//   S1: blur3d<6,1>  x -> xs        (x,y conv in LDS; z-conv via 7-deep REGISTER ring)
//   S2: gradprod3d   xs -> P[6]     (Sx/Dx + Sy/Dy in LDS; Dz/Sz via register rings; products)
//   S3: blur3d<24,6> P -> out       (grouped smoothing, all 6 channels, one dispatch)
// Each kernel: 2 barriers per slice, ~11 KB LDS -> 8 blocks/CU, XCD-swizzled grid.

constexpr int D  = 192;
constexpr int DD = D * D;                  // 36864
constexpr long long V = (long long)D * DD; // 7077888

// coef layout (floats):
//  [0..6] ga  [7..13] gb  [14..20] gc   (gauss z,y,x)
//  [21..29] az (9)  [30..34] bz (5)  [35..39] cz (5)
//  [40..44] ay (5)  [45..53] by (9)  [54..58] cy (5, dup)
//  [59..63] ax (5)  [64..68] bx (5)  [69..77] cx (9)
__global__ void setup_coef(const float* __restrict__ g3, const float* __restrict__ kz,
                           const float* __restrict__ ky, const float* __restrict__ kx,
                           float* __restrict__ c) {
    if (blockIdx.x != 0 || threadIdx.x != 0) return;
    float Tg = g3[0];
    for (int i = 0; i < 7; ++i) c[0 + i]  = g3[i * 49];
    for (int j = 0; j < 7; ++j) c[7 + j]  = g3[j * 7] / Tg;
    for (int k = 0; k < 7; ++k) c[14 + k] = g3[k] / Tg;
    float Tz = kz[0];                      // kz: [9,5,5]
    for (int i = 0; i < 9; ++i) c[21 + i] = kz[i * 25];
    for (int j = 0; j < 5; ++j) c[30 + j] = kz[j * 5] / Tz;
    for (int k = 0; k < 5; ++k) c[35 + k] = kz[k] / Tz;
    float Ty = ky[0];                      // ky: [5,9,5]
    for (int i = 0; i < 5; ++i) c[40 + i] = ky[i * 45];
    for (int j = 0; j < 9; ++j) c[45 + j] = ky[j * 5] / Ty;
    for (int k = 0; k < 5; ++k) c[54 + k] = ky[k] / Ty;
    float Tx = kx[0];                      // kx: [5,5,9]
    for (int i = 0; i < 5; ++i) c[59 + i] = kx[i * 45];
    for (int j = 0; j < 5; ++j) c[64 + j] = kx[j * 9] / Tx;
    for (int k = 0; k < 9; ++k) c[69 + k] = kx[k] / Tx;
}

// Load a (rows x 40)-float region of one z-slice into LDS, zero-padded.
__device__ inline void load_slice(const float* __restrict__ src, float* __restrict__ dst,
                                  int rows, int y0, int x0) {
    const int nq = rows * 10;
    for (int li = threadIdx.x; li < nq; li += 256) {
        const int r = li / 10, q = li % 10;
        const int gy = y0 + r, gx = x0 + q * 4;
        float4 v = {0.f, 0.f, 0.f, 0.f};
        if (gy >= 0 && gy < D) {
            if (gx >= 0 && gx + 3 < D) {
                v = *(const float4*)(src + gy * D + gx);
            } else {
                float* pv = (float*)&v;
                for (int j = 0; j < 4; ++j) {
                    const int g = gx + j;
                    if (g >= 0 && g < D) pv[j] = src[gy * D + g];
                }
            }
        }
        *(float4*)&dst[r * 40 + q * 4] = v;
    }
}

// ---- fused separable 3D blur, z-streaming, 32x32 tile, register z-ring ----
// 1D grid, XCD-swizzled; work = tile + 36*(ch + NCH*seg)
template <int SEG, int NCH>
__global__ __launch_bounds__(256) void blur3d(const float* __restrict__ in,
                                              float* __restrict__ out,
                                              const float* __restrict__ coef) {
    __shared__ float raw[38 * 40];
    __shared__ float xt[38][32];
    const int cpx = gridDim.x >> 3;
    int w = (blockIdx.x & 7) * cpx + (blockIdx.x >> 3);
    const int tile = w % 36; w /= 36;
    const int ch = w % NCH;
    const int seg = w / NCH;
    const int tx0 = (tile % 6) * 32, ty0 = (tile / 6) * 32;
    const int z0 = seg * SEG;
    const float* src = in + (long long)ch * V;
    float* dst = out + (long long)ch * V;
    float ga[7], gb[7], gc[7];
#pragma unroll
    for (int k = 0; k < 7; ++k) { ga[k] = coef[k]; gb[k] = coef[7 + k]; gc[k] = coef[14 + k]; }
    const int rr = threadIdx.x >> 3;          // 0..31
    const int cc = (threadIdx.x & 7) * 4;     // 0,4,..,28
    float4 ring[7];
#pragma unroll
    for (int k = 0; k < 7; ++k) ring[k] = make_float4(0.f, 0.f, 0.f, 0.f);

    for (int s = z0 - 3; s < z0 + SEG + 3; ++s) {
        const bool inz = (s >= 0 && s < D);
        if (inz) load_slice(src + (long long)s * DD, raw, 38, ty0 - 3, tx0 - 4);
        __syncthreads();                       // raw ready (and prior xt readers done)
        if (inz) {
            for (int li = threadIdx.x; li < 38 * 32; li += 256) {
                const int r = li >> 5, c = li & 31;
                float a = 0.f;
#pragma unroll
                for (int k = 0; k < 7; ++k) a += gc[k] * raw[r * 40 + c + 1 + k];
                xt[r][c] = a;
            }
        }
        __syncthreads();                       // xt ready (and raw readers done)
        float4 yv = make_float4(0.f, 0.f, 0.f, 0.f);
        if (inz) {
#pragma unroll
            for (int k = 0; k < 7; ++k) {
                const float4 v = *(const float4*)&xt[rr + k][cc];
                yv.x += gb[k] * v.x; yv.y += gb[k] * v.y;
                yv.z += gb[k] * v.z; yv.w += gb[k] * v.w;
            }
        }
#pragma unroll
        for (int k = 0; k < 6; ++k) ring[k] = ring[k + 1];
        ring[6] = yv;
        const int z = s - 3;
        if (z >= z0) {
            float4 a = make_float4(0.f, 0.f, 0.f, 0.f);
#pragma unroll
            for (int k = 0; k < 7; ++k) {
                a.x += ga[k] * ring[k].x; a.y += ga[k] * ring[k].y;
                a.z += ga[k] * ring[k].z; a.w += ga[k] * ring[k].w;
            }
            *(float4*)(dst + (long long)z * DD + (ty0 + rr) * D + tx0 + cc) = a;
        }
    }
}

// ---- fused gradients + products, z-streaming, 32x16 tile, register rings ----
// 1D grid, XCD-swizzled; work = tile + 72*seg
template <int SEG>
__global__ __launch_bounds__(256) void gradprod3d(const float* __restrict__ xs,
                                                  float* __restrict__ P,
                                                  const float* __restrict__ coef) {
    __shared__ float raw[24 * 40];
    __shared__ float X1[24][32];
    __shared__ float X2[24][32];
    const int cpx = gridDim.x >> 3;
    int w = (blockIdx.x & 7) * cpx + (blockIdx.x >> 3);
    const int tile = w % 72;
    const int seg = w / 72;
    const int tx0 = (tile % 6) * 32, ty0 = (tile / 6) * 16;
    const int z0 = seg * SEG;
    float az[9], ay[5], ax[5], bz[5], by[9], bx[5], czc[5], cxc[9];
#pragma unroll
    for (int k = 0; k < 9; ++k) az[k] = coef[21 + k];
#pragma unroll
    for (int k = 0; k < 5; ++k) ay[k] = coef[40 + k];
#pragma unroll
    for (int k = 0; k < 5; ++k) ax[k] = coef[59 + k];
#pragma unroll
    for (int k = 0; k < 5; ++k) bz[k] = coef[30 + k];
#pragma unroll
    for (int k = 0; k < 9; ++k) by[k] = coef[45 + k];
#pragma unroll
    for (int k = 0; k < 5; ++k) bx[k] = coef[64 + k];
#pragma unroll
    for (int k = 0; k < 5; ++k) czc[k] = coef[35 + k];
#pragma unroll
    for (int k = 0; k < 9; ++k) cxc[k] = coef[69 + k];
    const int rr = threadIdx.x >> 4;           // 0..15
    const int cc = (threadIdx.x & 15) * 2;     // 0,2,..,30
    float2 R1[9], R2[7], R3[7];
#pragma unroll
    for (int k = 0; k < 9; ++k) R1[k] = make_float2(0.f, 0.f);
#pragma unroll
    for (int k = 0; k < 7; ++k) { R2[k] = make_float2(0.f, 0.f); R3[k] = make_float2(0.f, 0.f); }

    for (int s = z0 - 4; s < z0 + SEG + 4; ++s) {
        const bool inz = (s >= 0 && s < D);
        if (inz) load_slice(xs + (long long)s * DD, raw, 24, ty0 - 4, tx0 - 4);
        __syncthreads();
        if (inz) {
            for (int li = threadIdx.x; li < 24 * 32; li += 256) {
                const int r = li >> 5, c = li & 31;
                float a1 = 0.f, a2 = 0.f;
#pragma unroll
                for (int k = 0; k < 5; ++k) a1 += czc[k] * raw[r * 40 + c + 2 + k];
#pragma unroll
                for (int k = 0; k < 9; ++k) a2 += cxc[k] * raw[r * 40 + c + k];
                X1[r][c] = a1;
                X2[r][c] = a2;
            }
        }
        __syncthreads();
        float2 t1 = make_float2(0.f, 0.f), t2 = t1, t3 = t1;
        if (inz) {
#pragma unroll
            for (int k = 0; k < 5; ++k) {
                const float2 v = *(const float2*)&X1[rr + 2 + k][cc];
                t1.x += bz[k] * v.x; t1.y += bz[k] * v.y;
            }
#pragma unroll
            for (int k = 0; k < 9; ++k) {
                const float2 v = *(const float2*)&X1[rr + k][cc];
                t2.x += by[k] * v.x; t2.y += by[k] * v.y;
            }
#pragma unroll
            for (int k = 0; k < 5; ++k) {
                const float2 v = *(const float2*)&X2[rr + 2 + k][cc];
                t3.x += bx[k] * v.x; t3.y += bx[k] * v.y;
            }
        }
#pragma unroll
        for (int k = 0; k < 8; ++k) R1[k] = R1[k + 1];
        R1[8] = t1;
#pragma unroll
        for (int k = 0; k < 6; ++k) { R2[k] = R2[k + 1]; R3[k] = R3[k + 1]; }
        R2[6] = t2; R3[6] = t3;
        const int z = s - 4;
        if (z >= z0) {
            float gz0 = 0.f, gz1 = 0.f, gy0 = 0.f, gy1 = 0.f, gx0 = 0.f, gx1 = 0.f;
#pragma unroll
            for (int k = 0; k < 9; ++k) { gz0 += az[k] * R1[k].x; gz1 += az[k] * R1[k].y; }
#pragma unroll
            for (int k = 0; k < 5; ++k) {
                gy0 += ay[k] * R2[k].x; gy1 += ay[k] * R2[k].y;
                gx0 += ax[k] * R3[k].x; gx1 += ax[k] * R3[k].y;
            }
            float* o = P + (long long)z * DD + (ty0 + rr) * D + tx0 + cc;
            float2 wv;
            wv.x = gz0 * gz0; wv.y = gz1 * gz1; *(float2*)(o + 0 * V) = wv;
            wv.x = gy0 * gz0; wv.y = gy1 * gz1; *(float2*)(o + 1 * V) = wv;
            wv.x = gx0 * gz0; wv.y = gx1 * gz1; *(float2*)(o + 2 * V) = wv;
            wv.x = gy0 * gy0; wv.y = gy1 * gy1; *(float2*)(o + 3 * V) = wv;
            wv.x = gx0 * gy0; wv.y = gx1 * gy1; *(float2*)(o + 4 * V) = wv;
            wv.x = gx0 * gx0; wv.y = gx1 * gx1; *(float2*)(o + 5 * V) = wv;
        }
    }
}

extern "C" void kernel_launch(void* const* d_in, const int* in_sizes, int n_in,
                              void* d_out, int out_size, void* d_ws, size_t ws_size,
                              hipStream_t stream) {
    const float* x  = (const float*)d_in[0];
    const float* g3 = (const float*)d_in[1];
    const float* kz = (const float*)d_in[2];
    const float* ky = (const float*)d_in[3];
    const float* kx = (const float*)d_in[4];
    float* out = (float*)d_out;

    float* coef = (float*)d_ws;
    float* P  = coef + 128;          // 6*V floats
    float* xs = P + 6 * V;           // V floats

    setup_coef<<<1, 64, 0, stream>>>(g3, kz, ky, kx, coef);

    // S1: Gaussian pre-smooth  x -> xs   (36 tiles x 32 segs = 1152 blocks)
    blur3d<6, 1><<<1152, 256, 0, stream>>>(x, xs, coef);

    // S2: gradients + products  xs -> P  (72 tiles x 16 segs = 1152 blocks)
    gradprod3d<12><<<1152, 256, 0, stream>>>(xs, P, coef);

    // S3: grouped smoothing  P -> out    (36 tiles x 6 ch x 8 segs = 1728 blocks)
    blur3d<24, 6><<<1728, 256, 0, stream>>>(P, out, coef);
}